// Round 5
// baseline (257.153 us; speedup 1.0000x reference)
//
#include <hip/hip_runtime.h>
#include <hip/hip_fp16.h>

#define N_NODES 100000
#define IN_F 128
#define NF 16      // HEADS * OUT_C
#define HEADS 8
#define NEG_SLOPE 0.2f
#define LOG2E 1.44269504f

#define RB 256          // nodes per bin (power of 2)
#define LOG_RB 8
#define NB 391          // ceil(100000/256)
#define SBITS 17        // src id bits (100000 < 2^17)
#define SMASK ((1u << SBITS) - 1)
#define BIN_C 4096      // edges per binning block (8/thread @512)
#define CAPB 9216       // per-bin capacity: mean 8184 + ~11 sigma; = 9*1024 exactly

// Node record rec[n]: 16 halves = 32B. Table = 3.2 MB -> L2-resident per XCD.

// ---------------------------------------------------------------------------
// phase1: h = x@W. 8 lanes per node, each lane computes an output PAIR.
// ---------------------------------------------------------------------------
__device__ __forceinline__ void phase1_body(
    int pb, const float* __restrict__ x, const float* __restrict__ W,
    __half* __restrict__ rec, float* Ws)
{
    int t = threadIdx.x;
    for (int i = t; i < IN_F * NF; i += 512) Ws[i] = W[i];
    __syncthreads();

    int tid  = pb * 512 + t;
    int node = tid >> 3;
    int j    = tid & 7;         // output-pair index (cols 2j, 2j+1)
    if (node >= N_NODES) return;

    const float4* xr4 = (const float4*)(x + (size_t)node * IN_F);
    const float2* Wp  = (const float2*)Ws;   // pair (k, j) at index k*8 + j

    float a0 = 0.f, b0 = 0.f, a1 = 0.f, b1 = 0.f;
    #pragma unroll 8
    for (int k4 = 0; k4 < IN_F / 4; ++k4) {
        float4 xv = xr4[k4];
        float2 w0 = Wp[(4 * k4 + 0) * 8 + j];
        float2 w1 = Wp[(4 * k4 + 1) * 8 + j];
        float2 w2 = Wp[(4 * k4 + 2) * 8 + j];
        float2 w3 = Wp[(4 * k4 + 3) * 8 + j];
        a0 = fmaf(xv.x, w0.x, a0); b0 = fmaf(xv.x, w0.y, b0);
        a1 = fmaf(xv.y, w1.x, a1); b1 = fmaf(xv.y, w1.y, b1);
        a0 = fmaf(xv.z, w2.x, a0); b0 = fmaf(xv.z, w2.y, b0);
        a1 = fmaf(xv.w, w3.x, a1); b1 = fmaf(xv.w, w3.y, b1);
    }
    __half2 hv = __floats2half2_rn(a0 + a1, b0 + b1);
    *(__half2*)(rec + (size_t)node * NF + 2 * j) = hv;
}

// ---------------------------------------------------------------------------
// Fused kernel: every 3rd block is bin-role (SB total), rest phase1 (PB).
// ---------------------------------------------------------------------------
__global__ __launch_bounds__(512) void fused_p1_bin(
    const int* __restrict__ ei, int* __restrict__ bin_cursor,
    unsigned* __restrict__ bins,
    const float* __restrict__ x, const float* __restrict__ W,
    __half* __restrict__ rec, int E, int SB)
{
    __shared__ union {
        struct {
            unsigned staging[BIN_C];        // 16 KB
            unsigned short bin16[BIN_C];    // 8 KB
            int hist[NB], offs[NB], cur[NB], gbase[NB]; // 6.3 KB
            int wsum[8], woff[8];
        } b;
        float Ws[IN_F * NF];
    } sm;

    int idx = blockIdx.x;
    bool is_bin = (idx % 3 == 0) && (idx / 3 < SB);
    if (!is_bin) {
        int cb = (idx + 2) / 3; if (cb > SB) cb = SB;
        phase1_body(idx - cb, x, W, rec, sm.Ws);
        return;
    }

    int t = threadIdx.x;
    int base = (idx / 3) * BIN_C;
    int n_valid = E - base;
    if (n_valid > BIN_C) n_valid = BIN_C;
    if (n_valid < 0) n_valid = 0;

    // load this block's edges once, coalesced, into registers
    int es[8], ed[8];
    #pragma unroll
    for (int k = 0; k < 8; ++k) {
        int i = t + 512 * k;
        bool v = i < n_valid;
        es[k] = v ? ei[base + i] : 0;
        ed[k] = v ? ei[E + base + i] : -1;
    }

    if (t < NB) sm.b.hist[t] = 0;
    __syncthreads();

    // A: histogram of dst bins (from registers)
    #pragma unroll
    for (int k = 0; k < 8; ++k)
        if (ed[k] >= 0) atomicAdd(&sm.b.hist[ed[k] >> LOG_RB], 1);
    __syncthreads();

    // B: block-wide exclusive scan of hist (1 bin/thread) + global reserve
    int sum = (t < NB) ? sm.b.hist[t] : 0;
    int lane = t & 63, wid = t >> 6;
    int v = sum;
    #pragma unroll
    for (int o = 1; o < 64; o <<= 1) {
        int u = __shfl_up(v, o);
        if (lane >= o) v += u;
    }
    if (lane == 63) sm.b.wsum[wid] = v;
    __syncthreads();
    if (t == 0) { int r = 0; for (int w = 0; w < 8; ++w) { sm.b.woff[w] = r; r += sm.b.wsum[w]; } }
    __syncthreads();
    int run = sm.b.woff[wid] + v - sum;
    if (t < NB) { sm.b.offs[t] = run; sm.b.cur[t] = run; }
    __syncthreads();
    if (t < NB)
        sm.b.gbase[t] = sm.b.hist[t] ? atomicAdd(&bin_cursor[t], sm.b.hist[t]) : 0;
    __syncthreads();

    // C: counting-sort into LDS staging (from registers)
    #pragma unroll
    for (int k = 0; k < 8; ++k) {
        if (ed[k] >= 0) {
            int b = ed[k] >> LOG_RB;
            int slot = atomicAdd(&sm.b.cur[b], 1);
            sm.b.staging[slot] = ((unsigned)(ed[k] & (RB - 1)) << SBITS) | (unsigned)es[k];
            sm.b.bin16[slot] = (unsigned short)b;
        }
    }
    __syncthreads();

    // D: coalesced write-out (runs of ~10.5 consecutive slots per bin)
    for (int i = t; i < n_valid; i += 512) {
        int b = sm.b.bin16[i];
        int pos = sm.b.gbase[b] + (i - sm.b.offs[b]);
        if (pos < CAPB) bins[(size_t)b * CAPB + pos] = sm.b.staging[i];
    }
}

// ---------------------------------------------------------------------------
// Accum: ONE 1024-thread block per 256-node bin (391 blocks). Phases A-C as
// before (rc[9] static register cache, LDS counting-sort). D-phase processes
// nodes in QUADS (4-deep cross-node software pipeline): all 4 nodes' staging
// reads, own-row loads and 16 rec loads are issued before any compute, so
// node d's L2 latency is covered by up to 3 nodes' compute (~540 cy) and the
// one cold stall amortizes over 4 nodes. Tails (deg>32) interleave all 4
// nodes in one rolled loop. Reductions for 4 nodes batch -> shuffle-latency
// ILP. __launch_bounds__(1024,8) pins VGPR<=64 to keep 2 blocks/CU.
// Prefetched ids CLAMPed to < N_NODES (pad garbage -> row 0, predicated off).
// ---------------------------------------------------------------------------
__global__ __launch_bounds__(1024, 8) void accum11_kernel(
    const unsigned* __restrict__ bins, const int* __restrict__ bin_cursor,
    const __half* __restrict__ rec,
    const float* __restrict__ att_src, const float* __restrict__ att_dst,
    const float* __restrict__ bias, const float* __restrict__ Wfc,
    const float* __restrict__ bfc, float* __restrict__ out)
{
    __shared__ unsigned staging[CAPB + 64];     // +64 pad: batch reads may run past cnt
    __shared__ int hist[RB], offs[RB + 1], cur[RB];

    int t = threadIdx.x;
    int b = blockIdx.x;
    int node0 = b * RB;

    if (t < RB) hist[t] = 0;
    __syncthreads();

    int cnt = bin_cursor[b];
    if (cnt > CAPB) cnt = CAPB;
    const unsigned* seg = bins + (size_t)b * CAPB;

    // cache segment in registers — STATIC indexing (9*1024 == CAPB)
    unsigned rc[9];
    #pragma unroll
    for (int k = 0; k < 9; ++k) {
        int i = t + 1024 * k;
        rc[k] = (i < cnt) ? seg[i] : 0xFFFFFFFFu;
    }

    // A: per-node histogram
    #pragma unroll
    for (int k = 0; k < 9; ++k)
        if (rc[k] != 0xFFFFFFFFu) atomicAdd(&hist[rc[k] >> SBITS], 1);
    __syncthreads();

    // B: scan of 256 counters by wave 0 (lane l owns nodes 4l..4l+3)
    if (t < 64) {
        int h0 = hist[4 * t], h1 = hist[4 * t + 1];
        int h2 = hist[4 * t + 2], h3 = hist[4 * t + 3];
        int v = h0 + h1 + h2 + h3;
        int inc = v;
        #pragma unroll
        for (int o = 1; o < 64; o <<= 1) {
            int u = __shfl_up(inc, o);
            if (t >= o) inc += u;
        }
        int ex = inc - v;
        offs[4 * t] = ex;     cur[4 * t] = ex;     ex += h0;
        offs[4 * t + 1] = ex; cur[4 * t + 1] = ex; ex += h1;
        offs[4 * t + 2] = ex; cur[4 * t + 2] = ex; ex += h2;
        offs[4 * t + 3] = ex; cur[4 * t + 3] = ex;
        if (t == 63) offs[RB] = inc;
    }
    __syncthreads();

    // C: sort src ids into per-node order in LDS
    #pragma unroll
    for (int k = 0; k < 9; ++k) {
        unsigned r = rc[k];
        if (r != 0xFFFFFFFFu) {
            int slot = atomicAdd(&cur[r >> SBITS], 1);
            staging[slot] = r & SMASK;
        }
    }
    __syncthreads();

    // D: wave-per-node gather, node-QUAD pipelined
    int wv = t >> 6, lane = t & 63;
    int h_id = lane & 7, e_off = lane >> 3;

    // lane constants: att coefficients (LOG2E folded), FC weights, biases
    float as0 = att_src[2 * h_id] * LOG2E, as1 = att_src[2 * h_id + 1] * LOG2E;
    float ad0 = att_dst[2 * h_id] * LOG2E, ad1 = att_dst[2 * h_id + 1] * LOG2E;
    float b0 = bias[2 * h_id], b1 = bias[2 * h_id + 1];
    float w00 = Wfc[(2 * h_id) * 2 + 0],     w01 = Wfc[(2 * h_id) * 2 + 1];
    float w10 = Wfc[(2 * h_id + 1) * 2 + 0], w11 = Wfc[(2 * h_id + 1) * 2 + 1];
    float c0 = bfc[0], c1 = bfc[1];

    const __half2* recp = (const __half2*)rec;   // row n at index n*8 + h_id

    // clamp prefetched id into the rec table (pad garbage -> node 0)
    #define CLAMP(s) ((s) < (unsigned)N_NODES ? (s) : 0u)
    #define EDGE(rh, pred, adst, den, num0, num1) { \
        float h0_ = __half2float((rh).x), h1_ = __half2float((rh).y); \
        float l_ = fmaf(as0, h0_, fmaf(as1, h1_, adst)); \
        l_ = l_ > 0.f ? l_ : NEG_SLOPE * l_; \
        float p_ = (pred) ? exp2f(l_) : 0.f; \
        den += p_; num0 = fmaf(p_, h0_, num0); num1 = fmaf(p_, h1_, num1); }

    // per-node compute block over the 4 upfront batches
    #define BODY4(r0, r1, r2, r3, deg, adst, den, n0, n1) \
        EDGE(r0, e_off      < deg, adst, den, n0, n1); \
        EDGE(r1, e_off + 8  < deg, adst, den, n0, n1); \
        EDGE(r2, e_off + 16 < deg, adst, den, n0, n1); \
        EDGE(r3, e_off + 24 < deg, adst, den, n0, n1);

    #define SELF(hx, hy, adst, den, n0, n1) { \
        float l = fmaf(as0, hx, fmaf(as1, hy, adst)); \
        l = l > 0.f ? l : NEG_SLOPE * l; \
        float p = exp2f(l); \
        den += p; n0 = fmaf(p, hx, n0); n1 = fmaf(p, hy, n1); }

    #define EPILOG(den, n0, n1, n, valid) { \
        float inv = 1.f / den; \
        float g0 = fmaf(n0, inv, b0); \
        float g1 = fmaf(n1, inv, b1); \
        float o0 = g0 * w00 + g1 * w10; \
        float o1 = g0 * w01 + g1 * w11; \
        o0 += __shfl_xor(o0, 1); o1 += __shfl_xor(o1, 1); \
        o0 += __shfl_xor(o0, 2); o1 += __shfl_xor(o1, 2); \
        o0 += __shfl_xor(o0, 4); o1 += __shfl_xor(o1, 4); \
        if (lane == 0 && (valid)) { \
            float2 res = { o0 + c0, o1 + c1 }; \
            *(float2*)(out + (size_t)(n) * 2) = res; } }

    for (int k = 0; k < RB / 16; k += 4) {
        int ln0 = wv + 16 * k;
        int n0_ = node0 + ln0, n1_ = n0_ + 16, n2_ = n0_ + 32, n3_ = n0_ + 48;
        bool v0 = n0_ < N_NODES, v1 = n1_ < N_NODES, v2 = n2_ < N_NODES, v3 = n3_ < N_NODES;

        int st0 = offs[ln0],      deg0 = offs[ln0 + 1]  - st0;
        int st1 = offs[ln0 + 16], deg1 = offs[ln0 + 17] - st1;
        int st2 = offs[ln0 + 32], deg2 = offs[ln0 + 33] - st2;
        int st3 = offs[ln0 + 48], deg3 = offs[ln0 + 49] - st3;

        // ---- issue phase: ALL 4 nodes' loads before any compute ----
        int i0 = st0 + e_off, i1 = st1 + e_off, i2 = st2 + e_off, i3 = st3 + e_off;
        unsigned sa0 = CLAMP(staging[i0]);
        unsigned sa1 = CLAMP(staging[i0 + 8]);
        unsigned sa2 = CLAMP(staging[i0 + 16]);
        unsigned sa3 = CLAMP(staging[i0 + 24]);
        unsigned sb0 = CLAMP(staging[i1]);
        unsigned sb1 = CLAMP(staging[i1 + 8]);
        unsigned sb2 = CLAMP(staging[i1 + 16]);
        unsigned sb3 = CLAMP(staging[i1 + 24]);
        unsigned sc0 = CLAMP(staging[i2]);
        unsigned sc1 = CLAMP(staging[i2 + 8]);
        unsigned sc2 = CLAMP(staging[i2 + 16]);
        unsigned sc3 = CLAMP(staging[i2 + 24]);
        unsigned sd0 = CLAMP(staging[i3]);
        unsigned sd1 = CLAMP(staging[i3 + 8]);
        unsigned sd2 = CLAMP(staging[i3 + 16]);
        unsigned sd3 = CLAMP(staging[i3 + 24]);

        __half2 hA = recp[(size_t)(v0 ? n0_ : 0) * 8 + h_id];
        __half2 hB = recp[(size_t)(v1 ? n1_ : 0) * 8 + h_id];
        __half2 hC = recp[(size_t)(v2 ? n2_ : 0) * 8 + h_id];
        __half2 hD = recp[(size_t)(v3 ? n3_ : 0) * 8 + h_id];

        __half2 rA0 = recp[(size_t)sa0 * 8 + h_id];
        __half2 rA1 = recp[(size_t)sa1 * 8 + h_id];
        __half2 rA2 = recp[(size_t)sa2 * 8 + h_id];
        __half2 rA3 = recp[(size_t)sa3 * 8 + h_id];
        __half2 rB0 = recp[(size_t)sb0 * 8 + h_id];
        __half2 rB1 = recp[(size_t)sb1 * 8 + h_id];
        __half2 rB2 = recp[(size_t)sb2 * 8 + h_id];
        __half2 rB3 = recp[(size_t)sb3 * 8 + h_id];
        __half2 rC0 = recp[(size_t)sc0 * 8 + h_id];
        __half2 rC1 = recp[(size_t)sc1 * 8 + h_id];
        __half2 rC2 = recp[(size_t)sc2 * 8 + h_id];
        __half2 rC3 = recp[(size_t)sc3 * 8 + h_id];
        __half2 rD0 = recp[(size_t)sd0 * 8 + h_id];
        __half2 rD1 = recp[(size_t)sd1 * 8 + h_id];
        __half2 rD2 = recp[(size_t)sd2 * 8 + h_id];
        __half2 rD3 = recp[(size_t)sd3 * 8 + h_id];

        // ---- node A compute (covers B/C/D loads in flight) ----
        float hA0 = __half2float(hA.x), hA1 = __half2float(hA.y);
        float adA = fmaf(ad0, hA0, ad1 * hA1);
        float dA = 0.f, nA0 = 0.f, nA1 = 0.f;
        BODY4(rA0, rA1, rA2, rA3, deg0, adA, dA, nA0, nA1);

        float hB0 = __half2float(hB.x), hB1 = __half2float(hB.y);
        float adB = fmaf(ad0, hB0, ad1 * hB1);
        float dB = 0.f, nB0 = 0.f, nB1 = 0.f;
        BODY4(rB0, rB1, rB2, rB3, deg1, adB, dB, nB0, nB1);

        float hC0 = __half2float(hC.x), hC1 = __half2float(hC.y);
        float adC = fmaf(ad0, hC0, ad1 * hC1);
        float dC = 0.f, nC0 = 0.f, nC1 = 0.f;
        BODY4(rC0, rC1, rC2, rC3, deg2, adC, dC, nC0, nC1);

        float hD0 = __half2float(hD.x), hD1 = __half2float(hD.y);
        float adD = fmaf(ad0, hD0, ad1 * hD1);
        float dD = 0.f, nD0 = 0.f, nD1 = 0.f;
        BODY4(rD0, rD1, rD2, rD3, deg3, adD, dD, nD0, nD1);

        // ---- interleaved tails (deg > 32): 4 nodes' loads alternate ----
        int m01 = deg0 > deg1 ? deg0 : deg1;
        int m23 = deg2 > deg3 ? deg2 : deg3;
        int mdeg = m01 > m23 ? m01 : m23;
        for (int i = 32 + e_off; i < mdeg; i += 8) {
            bool va = i < deg0, vb = i < deg1, vc = i < deg2, vd = i < deg3;
            unsigned sa = va ? staging[st0 + i] : 0u;   // valid entries already masked
            unsigned sb = vb ? staging[st1 + i] : 0u;
            unsigned sc = vc ? staging[st2 + i] : 0u;
            unsigned sd = vd ? staging[st3 + i] : 0u;
            __half2 ra = recp[(size_t)sa * 8 + h_id];
            __half2 rb = recp[(size_t)sb * 8 + h_id];
            __half2 rcx = recp[(size_t)sc * 8 + h_id];
            __half2 rd = recp[(size_t)sd * 8 + h_id];
            EDGE(ra, va, adA, dA, nA0, nA1);
            EDGE(rb, vb, adB, dB, nB0, nB1);
            EDGE(rcx, vc, adC, dC, nC0, nC1);
            EDGE(rd, vd, adD, dD, nD0, nD1);
        }

        // ---- batched reductions over e_off (12 independent chains) ----
        #pragma unroll
        for (int m = 8; m < 64; m <<= 1) {
            dA  += __shfl_xor(dA, m);  nA0 += __shfl_xor(nA0, m); nA1 += __shfl_xor(nA1, m);
            dB  += __shfl_xor(dB, m);  nB0 += __shfl_xor(nB0, m); nB1 += __shfl_xor(nB1, m);
            dC  += __shfl_xor(dC, m);  nC0 += __shfl_xor(nC0, m); nC1 += __shfl_xor(nC1, m);
            dD  += __shfl_xor(dD, m);  nD0 += __shfl_xor(nD0, m); nD1 += __shfl_xor(nD1, m);
        }
        // self-loops folded analytically
        SELF(hA0, hA1, adA, dA, nA0, nA1);
        SELF(hB0, hB1, adB, dB, nB0, nB1);
        SELF(hC0, hC1, adC, dC, nC0, nC1);
        SELF(hD0, hD1, adD, dD, nD0, nD1);
        // normalize + bias + FC, sum over heads, store
        EPILOG(dA, nA0, nA1, n0_, v0);
        EPILOG(dB, nB0, nB1, n1_, v1);
        EPILOG(dC, nC0, nC1, n2_, v2);
        EPILOG(dD, nD0, nD1, n3_, v3);
    }
    #undef EPILOG
    #undef SELF
    #undef BODY4
    #undef EDGE
    #undef CLAMP
}

// ---------------------------------------------------------------------------
extern "C" void kernel_launch(void* const* d_in, const int* in_sizes, int n_in,
                              void* d_out, int out_size, void* d_ws, size_t ws_size,
                              hipStream_t stream)
{
    const float* x       = (const float*)d_in[0];
    const int*   ei      = (const int*)d_in[1];   // [2, E]
    const float* W       = (const float*)d_in[3];
    const float* att_src = (const float*)d_in[4];
    const float* att_dst = (const float*)d_in[5];
    const float* bias    = (const float*)d_in[6];
    const float* Wfc     = (const float*)d_in[7];
    const float* bfc     = (const float*)d_in[8];
    float*       out     = (float*)d_out;

    const int E  = in_sizes[1] / 2;
    const int SB = (E + BIN_C - 1) / BIN_C;            // bin-role blocks (782)
    const int PB = (N_NODES * 8 + 511) / 512;          // phase1-role blocks (1563)

    // ws layout: rec f16[N*16] (3.2MB) | bin_cursor i32[NB] | (4KB align) |
    //            bins u32[NB*CAPB] (~14.4MB)
    __half* rec        = (__half*)d_ws;
    int*    bin_cursor = (int*)((char*)d_ws + (size_t)N_NODES * NF * 2);
    size_t  bins_off   = (((size_t)((char*)bin_cursor - (char*)d_ws)) + NB * 4 + 4095) & ~(size_t)4095;
    unsigned* bins     = (unsigned*)((char*)d_ws + bins_off);

    hipMemsetAsync(bin_cursor, 0, NB * sizeof(int), stream);

    fused_p1_bin<<<SB + PB, 512, 0, stream>>>(
        ei, bin_cursor, bins, x, W, rec, E, SB);
    accum11_kernel<<<NB, 1024, 0, stream>>>(
        bins, bin_cursor, rec, att_src, att_dst, bias, Wfc, bfc, out);
}

// Round 6
// 186.828 us; speedup vs baseline: 1.3764x; 1.3764x over previous
//
#include <hip/hip_runtime.h>
#include <hip/hip_fp16.h>

#define N_NODES 100000
#define IN_F 128
#define NF 16      // HEADS * OUT_C
#define HEADS 8
#define NEG_SLOPE 0.2f
#define LOG2E 1.44269504f

#define RB 196          // nodes per bin (NON-pow2: NB=511 ~= 2 blocks/CU exactly)
#define NB 511          // ceil(100000/196); 510*196=99960, bin 510 has 40 nodes
#define SBITS 17        // src id bits (100000 < 2^17)
#define SMASK ((1u << SBITS) - 1)
#define BIN_C 4096      // edges per binning block (8/thread @512)
#define CAPB 7040       // per-bin capacity: mean 6272 + 9.7 sigma; rc[7] covers it

// Node record rec[n]: 16 halves = 32B. Table = 3.2 MB -> L2-resident per XCD.

// ---------------------------------------------------------------------------
// phase1: h = x@W. 8 lanes per node, each lane computes an output PAIR.
// ---------------------------------------------------------------------------
__device__ __forceinline__ void phase1_body(
    int pb, const float* __restrict__ x, const float* __restrict__ W,
    __half* __restrict__ rec, float* Ws)
{
    int t = threadIdx.x;
    for (int i = t; i < IN_F * NF; i += 512) Ws[i] = W[i];
    __syncthreads();

    int tid  = pb * 512 + t;
    int node = tid >> 3;
    int j    = tid & 7;         // output-pair index (cols 2j, 2j+1)
    if (node >= N_NODES) return;

    const float4* xr4 = (const float4*)(x + (size_t)node * IN_F);
    const float2* Wp  = (const float2*)Ws;   // pair (k, j) at index k*8 + j

    float a0 = 0.f, b0 = 0.f, a1 = 0.f, b1 = 0.f;
    #pragma unroll 8
    for (int k4 = 0; k4 < IN_F / 4; ++k4) {
        float4 xv = xr4[k4];
        float2 w0 = Wp[(4 * k4 + 0) * 8 + j];
        float2 w1 = Wp[(4 * k4 + 1) * 8 + j];
        float2 w2 = Wp[(4 * k4 + 2) * 8 + j];
        float2 w3 = Wp[(4 * k4 + 3) * 8 + j];
        a0 = fmaf(xv.x, w0.x, a0); b0 = fmaf(xv.x, w0.y, b0);
        a1 = fmaf(xv.y, w1.x, a1); b1 = fmaf(xv.y, w1.y, b1);
        a0 = fmaf(xv.z, w2.x, a0); b0 = fmaf(xv.z, w2.y, b0);
        a1 = fmaf(xv.w, w3.x, a1); b1 = fmaf(xv.w, w3.y, b1);
    }
    __half2 hv = __floats2half2_rn(a0 + a1, b0 + b1);
    *(__half2*)(rec + (size_t)node * NF + 2 * j) = hv;
}

// ---------------------------------------------------------------------------
// Fused kernel: every 3rd block is bin-role (SB total), rest phase1 (PB).
// Bin role: load 4096 edges into registers; LDS counting-sort by dst bin
// (511 bins of 196 nodes, bin = d/196 via magic-mul); reserve per-(block,bin)
// ranges with one global atomic each; write packed (d_local<<17 | src).
// ---------------------------------------------------------------------------
__global__ __launch_bounds__(512) void fused_p1_bin(
    const int* __restrict__ ei, int* __restrict__ bin_cursor,
    unsigned* __restrict__ bins,
    const float* __restrict__ x, const float* __restrict__ W,
    __half* __restrict__ rec, int E, int SB)
{
    __shared__ union {
        struct {
            unsigned staging[BIN_C];        // 16 KB
            unsigned short bin16[BIN_C];    // 8 KB
            int hist[NB], offs[NB], cur[NB], gbase[NB]; // 8.2 KB
            int wsum[8], woff[8];
        } b;
        float Ws[IN_F * NF];
    } sm;

    int idx = blockIdx.x;
    bool is_bin = (idx % 3 == 0) && (idx / 3 < SB);
    if (!is_bin) {
        int cb = (idx + 2) / 3; if (cb > SB) cb = SB;
        phase1_body(idx - cb, x, W, rec, sm.Ws);
        return;
    }

    int t = threadIdx.x;
    int base = (idx / 3) * BIN_C;
    int n_valid = E - base;
    if (n_valid > BIN_C) n_valid = BIN_C;
    if (n_valid < 0) n_valid = 0;

    // load this block's edges once, coalesced, into registers
    int es[8], ed[8];
    #pragma unroll
    for (int k = 0; k < 8; ++k) {
        int i = t + 512 * k;
        bool v = i < n_valid;
        es[k] = v ? ei[base + i] : 0;
        ed[k] = v ? ei[E + base + i] : -1;
    }

    if (t < NB) sm.b.hist[t] = 0;
    __syncthreads();

    // A: histogram of dst bins (from registers); bin = d/196 (magic-mul)
    #pragma unroll
    for (int k = 0; k < 8; ++k)
        if (ed[k] >= 0) atomicAdd(&sm.b.hist[(unsigned)ed[k] / RB], 1);
    __syncthreads();

    // B: block-wide exclusive scan of hist (1 bin/thread) + global reserve
    int sum = (t < NB) ? sm.b.hist[t] : 0;
    int lane = t & 63, wid = t >> 6;
    int v = sum;
    #pragma unroll
    for (int o = 1; o < 64; o <<= 1) {
        int u = __shfl_up(v, o);
        if (lane >= o) v += u;
    }
    if (lane == 63) sm.b.wsum[wid] = v;
    __syncthreads();
    if (t == 0) { int r = 0; for (int w = 0; w < 8; ++w) { sm.b.woff[w] = r; r += sm.b.wsum[w]; } }
    __syncthreads();
    int run = sm.b.woff[wid] + v - sum;
    if (t < NB) { sm.b.offs[t] = run; sm.b.cur[t] = run; }
    __syncthreads();
    if (t < NB)
        sm.b.gbase[t] = sm.b.hist[t] ? atomicAdd(&bin_cursor[t], sm.b.hist[t]) : 0;
    __syncthreads();

    // C: counting-sort into LDS staging (from registers)
    #pragma unroll
    for (int k = 0; k < 8; ++k) {
        if (ed[k] >= 0) {
            unsigned d = (unsigned)ed[k];
            unsigned bb = d / RB;
            unsigned dl = d - bb * RB;          // local node id, 0..195
            int slot = atomicAdd(&sm.b.cur[bb], 1);
            sm.b.staging[slot] = (dl << SBITS) | (unsigned)es[k];
            sm.b.bin16[slot] = (unsigned short)bb;
        }
    }
    __syncthreads();

    // D: coalesced write-out (runs of ~8 consecutive slots per bin)
    for (int i = t; i < n_valid; i += 512) {
        int b = sm.b.bin16[i];
        int pos = sm.b.gbase[b] + (i - sm.b.offs[b]);
        if (pos < CAPB) bins[(size_t)b * CAPB + pos] = sm.b.staging[i];
    }
}

// ---------------------------------------------------------------------------
// Accum: ONE 1024-thread block per 196-node bin, grid 511 = 255 CUs x 2 + 1
// -> ~100% CU balance (vs 76% at NB=391), doubling resident waves in the
// latency-bound D-phase. Phases A-C: rc[7] static register cache + LDS
// counting-sort. D-phase: round-4's PAIR pipeline (depth 2 — depth 4 spilled
// to scratch under the 64-VGPR cap, round-5 FETCH_SIZE x12 regression).
// Prefetched ids CLAMPed to < N_NODES (pad garbage -> row 0, predicated off).
// ---------------------------------------------------------------------------
__global__ __launch_bounds__(1024, 8) void accum12_kernel(
    const unsigned* __restrict__ bins, const int* __restrict__ bin_cursor,
    const __half* __restrict__ rec,
    const float* __restrict__ att_src, const float* __restrict__ att_dst,
    const float* __restrict__ bias, const float* __restrict__ Wfc,
    const float* __restrict__ bfc, float* __restrict__ out)
{
    __shared__ unsigned staging[CAPB + 64];     // +64 pad: batch reads may run past cnt
    __shared__ int hist[RB], offs[RB + 1], cur[RB];

    int t = threadIdx.x;
    int b = blockIdx.x;
    int node0 = b * RB;

    if (t < RB) hist[t] = 0;
    __syncthreads();

    int cnt = bin_cursor[b];
    if (cnt > CAPB) cnt = CAPB;
    const unsigned* seg = bins + (size_t)b * CAPB;

    // cache segment in registers — STATIC indexing (7*1024 >= CAPB)
    unsigned rc[7];
    #pragma unroll
    for (int k = 0; k < 7; ++k) {
        int i = t + 1024 * k;
        rc[k] = (i < cnt) ? seg[i] : 0xFFFFFFFFu;
    }

    // A: per-node histogram
    #pragma unroll
    for (int k = 0; k < 7; ++k)
        if (rc[k] != 0xFFFFFFFFu) atomicAdd(&hist[rc[k] >> SBITS], 1);
    __syncthreads();

    // B: scan of 196 counters by wave 0 (lane l<49 owns nodes 4l..4l+3)
    if (t < 49) {
        int h0 = hist[4 * t], h1 = hist[4 * t + 1];
        int h2 = hist[4 * t + 2], h3 = hist[4 * t + 3];
        int v = h0 + h1 + h2 + h3;
        int inc = v;
        #pragma unroll
        for (int o = 1; o < 64; o <<= 1) {
            int u = __shfl_up(inc, o);
            if (t >= o) inc += u;
        }
        int ex = inc - v;
        offs[4 * t] = ex;     cur[4 * t] = ex;     ex += h0;
        offs[4 * t + 1] = ex; cur[4 * t + 1] = ex; ex += h1;
        offs[4 * t + 2] = ex; cur[4 * t + 2] = ex; ex += h2;
        offs[4 * t + 3] = ex; cur[4 * t + 3] = ex;
        if (t == 48) offs[RB] = inc;
    }
    __syncthreads();

    // C: sort src ids into per-node order in LDS
    #pragma unroll
    for (int k = 0; k < 7; ++k) {
        unsigned r = rc[k];
        if (r != 0xFFFFFFFFu) {
            int slot = atomicAdd(&cur[r >> SBITS], 1);
            staging[slot] = r & SMASK;
        }
    }
    __syncthreads();

    // D: wave-per-node gather, node-PAIR pipelined
    int wv = t >> 6, lane = t & 63;
    int h_id = lane & 7, e_off = lane >> 3;

    // lane constants: att coefficients (LOG2E folded), FC weights, biases
    float as0 = att_src[2 * h_id] * LOG2E, as1 = att_src[2 * h_id + 1] * LOG2E;
    float ad0 = att_dst[2 * h_id] * LOG2E, ad1 = att_dst[2 * h_id + 1] * LOG2E;
    float b0 = bias[2 * h_id], b1 = bias[2 * h_id + 1];
    float w00 = Wfc[(2 * h_id) * 2 + 0],     w01 = Wfc[(2 * h_id) * 2 + 1];
    float w10 = Wfc[(2 * h_id + 1) * 2 + 0], w11 = Wfc[(2 * h_id + 1) * 2 + 1];
    float c0 = bfc[0], c1 = bfc[1];

    const __half2* recp = (const __half2*)rec;   // row n at index n*8 + h_id

    // clamp prefetched id into the rec table (pad garbage -> node 0)
    #define CLAMP(s) ((s) < (unsigned)N_NODES ? (s) : 0u)
    #define EDGE(rh, pred, adst, den, num0, num1) { \
        float h0_ = __half2float((rh).x), h1_ = __half2float((rh).y); \
        float l_ = fmaf(as0, h0_, fmaf(as1, h1_, adst)); \
        l_ = l_ > 0.f ? l_ : NEG_SLOPE * l_; \
        float p_ = (pred) ? exp2f(l_) : 0.f; \
        den += p_; num0 = fmaf(p_, h0_, num0); num1 = fmaf(p_, h1_, num1); }

    // node slots: ln = wv + 16*k for k = 0..12 (196/16 = 12.25); guard ln<RB
    for (int k = 0; k < 13; k += 2) {
        int lnA = wv + 16 * k, lnB = lnA + 16;
        bool vA = lnA < RB, vB = lnB < RB;
        int nA = node0 + lnA, nB = node0 + lnB;
        vA = vA && (nA < N_NODES);
        vB = vB && (nB < N_NODES);
        if (!vA) break;          // slots are monotone: if A invalid, B is too

        int stA = offs[lnA], degA = offs[lnA + 1] - stA;
        int stB = vB ? offs[lnB] : 0;
        int degB = vB ? (offs[lnB + 1] - stB) : 0;

        // ---- issue phase: ALL of A's and B's loads before any compute ----
        int iA = stA + e_off, iB = stB + e_off;
        unsigned sA0 = CLAMP(staging[iA]);
        unsigned sA1 = CLAMP(staging[iA + 8]);
        unsigned sA2 = CLAMP(staging[iA + 16]);
        unsigned sA3 = CLAMP(staging[iA + 24]);
        unsigned sB0 = CLAMP(staging[iB]);
        unsigned sB1 = CLAMP(staging[iB + 8]);
        unsigned sB2 = CLAMP(staging[iB + 16]);
        unsigned sB3 = CLAMP(staging[iB + 24]);

        __half2 hnA = recp[(size_t)nA * 8 + h_id];
        __half2 hnB = recp[(size_t)(vB ? nB : nA) * 8 + h_id];

        __half2 rA0 = recp[(size_t)sA0 * 8 + h_id];
        __half2 rA1 = recp[(size_t)sA1 * 8 + h_id];
        __half2 rA2 = recp[(size_t)sA2 * 8 + h_id];
        __half2 rA3 = recp[(size_t)sA3 * 8 + h_id];
        __half2 rB0 = recp[(size_t)sB0 * 8 + h_id];
        __half2 rB1 = recp[(size_t)sB1 * 8 + h_id];
        __half2 rB2 = recp[(size_t)sB2 * 8 + h_id];
        __half2 rB3 = recp[(size_t)sB3 * 8 + h_id];

        // ---- node A compute (covers B's loads in flight) ----
        float hnA0 = __half2float(hnA.x), hnA1 = __half2float(hnA.y);
        float adstA = fmaf(ad0, hnA0, ad1 * hnA1);
        float denA = 0.f, n0A = 0.f, n1A = 0.f;
        EDGE(rA0, e_off      < degA, adstA, denA, n0A, n1A);
        EDGE(rA1, e_off + 8  < degA, adstA, denA, n0A, n1A);
        EDGE(rA2, e_off + 16 < degA, adstA, denA, n0A, n1A);
        EDGE(rA3, e_off + 24 < degA, adstA, denA, n0A, n1A);

        // ---- node B compute ----
        float hnB0 = __half2float(hnB.x), hnB1 = __half2float(hnB.y);
        float adstB = fmaf(ad0, hnB0, ad1 * hnB1);
        float denB = 0.f, n0B = 0.f, n1B = 0.f;
        EDGE(rB0, e_off      < degB, adstB, denB, n0B, n1B);
        EDGE(rB1, e_off + 8  < degB, adstB, denB, n0B, n1B);
        EDGE(rB2, e_off + 16 < degB, adstB, denB, n0B, n1B);
        EDGE(rB3, e_off + 24 < degB, adstB, denB, n0B, n1B);

        // ---- interleaved tails (deg > 32): A and B loads alternate ----
        if (degA > 32 || degB > 32) {
            for (int i = 32 + e_off; i < degA || i < degB; i += 8) {
                bool ta = i < degA, tb = i < degB;
                unsigned sa = ta ? staging[stA + i] : 0u;   // valid entries already masked
                unsigned sb = tb ? staging[stB + i] : 0u;
                __half2 ra = recp[(size_t)sa * 8 + h_id];
                __half2 rb = recp[(size_t)sb * 8 + h_id];
                EDGE(ra, ta, adstA, denA, n0A, n1A);
                EDGE(rb, tb, adstB, denB, n0B, n1B);
            }
        }

        // ---- reductions (A and B independent -> ILP) ----
        #pragma unroll
        for (int m = 8; m < 64; m <<= 1) {
            denA += __shfl_xor(denA, m);
            n0A  += __shfl_xor(n0A, m);
            n1A  += __shfl_xor(n1A, m);
            denB += __shfl_xor(denB, m);
            n0B  += __shfl_xor(n0B, m);
            n1B  += __shfl_xor(n1B, m);
        }
        // self-loops folded analytically
        {
            float l = fmaf(as0, hnA0, fmaf(as1, hnA1, adstA));
            l = l > 0.f ? l : NEG_SLOPE * l;
            float p = exp2f(l);
            denA += p; n0A = fmaf(p, hnA0, n0A); n1A = fmaf(p, hnA1, n1A);
        }
        {
            float l = fmaf(as0, hnB0, fmaf(as1, hnB1, adstB));
            l = l > 0.f ? l : NEG_SLOPE * l;
            float p = exp2f(l);
            denB += p; n0B = fmaf(p, hnB0, n0B); n1B = fmaf(p, hnB1, n1B);
        }
        // normalize + bias + FC, sum over heads — node A
        {
            float inv = 1.f / denA;
            float g0 = fmaf(n0A, inv, b0);
            float g1 = fmaf(n1A, inv, b1);
            float o0 = g0 * w00 + g1 * w10;
            float o1 = g0 * w01 + g1 * w11;
            #pragma unroll
            for (int m = 1; m < 8; m <<= 1) {
                o0 += __shfl_xor(o0, m);
                o1 += __shfl_xor(o1, m);
            }
            if (lane == 0) {
                float2 res = { o0 + c0, o1 + c1 };
                *(float2*)(out + (size_t)nA * 2) = res;
            }
        }
        // node B
        if (vB) {
            float inv = 1.f / denB;
            float g0 = fmaf(n0B, inv, b0);
            float g1 = fmaf(n1B, inv, b1);
            float o0 = g0 * w00 + g1 * w10;
            float o1 = g0 * w01 + g1 * w11;
            #pragma unroll
            for (int m = 1; m < 8; m <<= 1) {
                o0 += __shfl_xor(o0, m);
                o1 += __shfl_xor(o1, m);
            }
            if (lane == 0) {
                float2 res = { o0 + c0, o1 + c1 };
                *(float2*)(out + (size_t)nB * 2) = res;
            }
        }
    }
    #undef EDGE
    #undef CLAMP
}

// ---------------------------------------------------------------------------
extern "C" void kernel_launch(void* const* d_in, const int* in_sizes, int n_in,
                              void* d_out, int out_size, void* d_ws, size_t ws_size,
                              hipStream_t stream)
{
    const float* x       = (const float*)d_in[0];
    const int*   ei      = (const int*)d_in[1];   // [2, E]
    const float* W       = (const float*)d_in[3];
    const float* att_src = (const float*)d_in[4];
    const float* att_dst = (const float*)d_in[5];
    const float* bias    = (const float*)d_in[6];
    const float* Wfc     = (const float*)d_in[7];
    const float* bfc     = (const float*)d_in[8];
    float*       out     = (float*)d_out;

    const int E  = in_sizes[1] / 2;
    const int SB = (E + BIN_C - 1) / BIN_C;            // bin-role blocks (782)
    const int PB = (N_NODES * 8 + 511) / 512;          // phase1-role blocks (1563)

    // ws layout: rec f16[N*16] (3.2MB) | bin_cursor i32[NB] | (4KB align) |
    //            bins u32[NB*CAPB] (14.39MB)
    __half* rec        = (__half*)d_ws;
    int*    bin_cursor = (int*)((char*)d_ws + (size_t)N_NODES * NF * 2);
    size_t  bins_off   = (((size_t)((char*)bin_cursor - (char*)d_ws)) + NB * 4 + 4095) & ~(size_t)4095;
    unsigned* bins     = (unsigned*)((char*)d_ws + bins_off);

    hipMemsetAsync(bin_cursor, 0, NB * sizeof(int), stream);

    fused_p1_bin<<<SB + PB, 512, 0, stream>>>(
        ei, bin_cursor, bins, x, W, rec, E, SB);
    accum12_kernel<<<NB, 1024, 0, stream>>>(
        bins, bin_cursor, rec, att_src, att_dst, bias, Wfc, bfc, out);
}